// Round 8
// baseline (128.303 us; speedup 1.0000x reference)
//
#include <hip/hip_runtime.h>
#include <hip/hip_bf16.h>
#include <stdint.h>

// B=32, C=256, H=W=32, 3x3 conv pad 1 -> implicit GEMM in INT8.
// M = 32768 (b,h,w), N = 256 (co), K = 2304; k = (kh*3+kw)*256 + ci.
//
// Locked structure (R1/R2/R4 regressed): 128x128 block, 8 waves 2m x 4n,
// 4 waves/SIMD; latency-bound, TLP is the latency-hiding resource.
// R5 (win): B distance-2 prefetch + XCD-chunked block swizzle.
// R7 (tie, kept): x-quant fused into GEMM staging; xpad deleted.
// R8: MFMA shape 16x16x64 -> 32x32x32 i8 (4404 vs 3944 TOPS measured).
// Halves MFMA instruction count (4/kt/wave instead of 8) in the issue-bound
// K-loop; iso-register (acc 32, aP 32, bP 24), same As layout. Wave m-frag =
// one full h-row (32 w). wquant layout + epilogue remapped to the 32x32
// fragment order (C/D: col=lane&31, row=(reg&3)+8*(reg>>2)+4*(lane>>5)).

typedef int i32x4 __attribute__((ext_vector_type(4)));
typedef int i32x16 __attribute__((ext_vector_type(16)));
typedef float f32x4 __attribute__((ext_vector_type(4)));

// Weight quant: block co = 0..255 -> ternary int8 in 32x32x32-fragment order.
// Block (co>>5, kt, s) of 1KB: lane l = ck*32 + (co&31), byte j =
// Wq[co][k = kt*64 + s*32 + ck*16 + j]   (ck = l>>5).
__global__ __launch_bounds__(256) void wquant_kernel(
    const float* __restrict__ w, signed char* __restrict__ wq)
{
    __shared__ signed char wt[9 * 256];       // [khkw*256 + ci] = [k]
    const int t = threadIdx.x;
    const int co = blockIdx.x;
#pragma unroll
    for (int p = 0; p < 9; ++p) {
        const int idx = p * 256 + t;          // = ci*9 + khkw
        const float v = w[co * 2304 + idx];
        const int ci = idx / 9;
        const int khkw = idx - 9 * ci;
        const float q = fminf(fmaxf(rintf(v), -1.f), 1.f);
        wt[khkw * 256 + ci] = (signed char)(int)q;
    }
    __syncthreads();
    if (t < 144) {                            // t = kt*4 + kq; k16 = kq
        const int kt = t >> 2, kq = t & 3;
        const uint4 v = *(const uint4*)(wt + t * 16);   // k = t*16 .. +15
        // s = kq>>1 (which 32-k half), ck = kq&1 (which 16B within it)
        *(uint4*)(wq + (((size_t)(co >> 5) * 72 + kt * 2 + (kq >> 1)) << 10)
                     + (((kq & 1) << 5) + (co & 31)) * 16) = v;
    }
}

// Fused conv: grid 512 (256 m-tiles x 2 n-tiles), 512 threads = 8 waves
// (2m x 4n). Wave = 64m x 32n: 2 m-frags (one h-row each) x 1 n-frag of
// 32x32x32 i8. LDS: A halo, 6 rows x 34 wp x 256 ci = 52,224 B, xor-swizzled
// chunks, built in-kernel from x (quant fused into staging).
__global__ __launch_bounds__(512, 4) void conv_gemm_kernel(
    const float* __restrict__ x, const signed char* __restrict__ wqm,
    const float* __restrict__ gamma, const float* __restrict__ beta,
    const float* __restrict__ mean, const float* __restrict__ var,
    float* __restrict__ out)
{
    __shared__ signed char As[6 * 34 * 256];   // [r=hh*34+wp][chunk ^ (r&15)][16]

    const int tid = threadIdx.x;
    const int wv = tid >> 6;
    const int lane = tid & 63;
    const int l32 = lane & 31;
    const int lhi = lane >> 5;                 // k-chunk selector (16B half)

    // XCD-chunked bijective swizzle (512 = 8 x 64): XCD g gets swz 64g..64g+63.
    const int bid = (int)blockIdx.x;
    const int swz = (bid & 7) * 64 + (bid >> 3);

    const int mt = swz >> 1;
    const int n0 = (swz & 1) * 128;
    const int b = mt >> 3;
    const int h0 = (mt & 7) * 4;
    const int wave_m = wv & 1;    // 2 waves over m (64 each = 2 h-rows)
    const int wave_n = wv >> 1;   // 4 waves over n (32 each)

    // B pointer + first prefetches issued before staging (independent of LDS)
    const signed char* bp = wqm
        + (((size_t)((n0 >> 5) + wave_n) * 72) << 10) + lane * 16;

    i32x4 aP[2][2][2], bP[3][2];               // A dbuf [frag][kstep]; B dist-2

#define LOAD_B(kt, dst) { dst[0] = *(const i32x4*)(bp + ((kt) * 2 + 0) * 1024); \
                          dst[1] = *(const i32x4*)(bp + ((kt) * 2 + 1) * 1024); }
#define LOAD_A(kt, dst) { const int khkw = (kt) >> 2; \
                          const int kh = khkw / 3; \
                          const int kw = khkw - 3 * kh; \
                          const int roff = kh * 34 + kw; \
                          _Pragma("unroll") \
                          for (int i = 0; i < 2; ++i) { \
                              const int r = r0[i] + roff; \
                              _Pragma("unroll") \
                              for (int s = 0; s < 2; ++s) { \
                                  const int cb = ((kt) & 3) * 4 + s * 2 + lhi; \
                                  dst[i][s] = *(const i32x4*)(As + r * 256 + ((cb ^ (r & 15)) << 4)); \
                              } } }
#define MFMA(af, bf) { _Pragma("unroll") \
                       for (int s = 0; s < 2; ++s) \
                           _Pragma("unroll") \
                           for (int i = 0; i < 2; ++i) \
                               acc[i] = __builtin_amdgcn_mfma_i32_32x32x32_i8(af[i][s], bf[s], acc[i], 0, 0, 0); }

    LOAD_B(0, bP[0])
    LOAD_B(1, bP[1])

    // ---- staging: zero borders ----
    const uint4 z = {0u, 0u, 0u, 0u};
    if (tid < 192) {                           // wp=0,33 cols of the 6 rows
        const int pair = tid >> 4;             // (hh 0..5) x (wp 0|33)
        const int hh = pair >> 1;
        const int wp = (pair & 1) * 33;
        const bool covered = (h0 == 0 && hh == 0) || (h0 == 28 && hh == 5);
        if (!covered) {
            const int r = hh * 34 + wp;
            const int ch = tid & 15;
            *(uint4*)(As + r * 256 + ((ch ^ (r & 15)) << 4)) = z;
        }
    }
    if (h0 == 0) {                             // halo row above image: all zero
        for (int i = tid; i < 544; i += 512) {
            const int r = i >> 4;
            const int ch = i & 15;
            *(uint4*)(As + r * 256 + ((ch ^ (r & 15)) << 4)) = z;
        }
    }
    if (h0 == 28) {                            // halo row below image: all zero
        for (int i = tid; i < 544; i += 512) {
            const int r = 5 * 34 + (i >> 4);
            const int ch = i & 15;
            *(uint4*)(As + r * 256 + ((ch ^ (r & 15)) << 4)) = z;
        }
    }

    // ---- staging: fused x-quant, 4ci x 4w block per thread per row ----
    const int cib = tid >> 3;                  // 0..63 (ci0 = 4*cib)
    const int w4 = tid & 7;                    // 0..7  (w = w4*4 .. +3)
#pragma unroll
    for (int hh = 0; hh < 6; ++hh) {
        const int h = h0 + hh - 1;
        if (h < 0 || h > 31) continue;         // block-uniform branch
        const float* xb = x + ((size_t)(b * 256) * 32 + h) * 32;
        unsigned row[4];                       // row[j] byte k = Q[ci0+j][w4*4+k]
#pragma unroll
        for (int j = 0; j < 4; ++j) {
            const f32x4 v = *(const f32x4*)(xb + (size_t)(cib * 4 + j) * 1024 + w4 * 4);
            unsigned p = 0;
#pragma unroll
            for (int k = 0; k < 4; ++k) {
                const float q = fminf(fmaxf(rintf(__fmul_rn(v[k], 128.f)), -128.f), 127.f);
                p |= ((unsigned)(unsigned char)(signed char)(int)q) << (8 * k);
            }
            row[j] = p;
        }
        const unsigned ab_lo = __builtin_amdgcn_perm(row[1], row[0], 0x05010400u);
        const unsigned ab_hi = __builtin_amdgcn_perm(row[1], row[0], 0x07030602u);
        const unsigned cd_lo = __builtin_amdgcn_perm(row[3], row[2], 0x05010400u);
        const unsigned cd_hi = __builtin_amdgcn_perm(row[3], row[2], 0x07030602u);
        unsigned col[4];
        col[0] = __builtin_amdgcn_perm(cd_lo, ab_lo, 0x05040100u);
        col[1] = __builtin_amdgcn_perm(cd_lo, ab_lo, 0x07060302u);
        col[2] = __builtin_amdgcn_perm(cd_hi, ab_hi, 0x05040100u);
        col[3] = __builtin_amdgcn_perm(cd_hi, ab_hi, 0x07060302u);
#pragma unroll
        for (int r = 0; r < 4; ++r) {
            const int rr = hh * 34 + w4 * 4 + r + 1;   // wp = w+1 in 1..32
            *(unsigned*)(As + rr * 256 + (((cib >> 2) ^ (rr & 15)) << 4) + (cib & 3) * 4) = col[r];
        }
    }
    __syncthreads();   // the ONLY barrier

    // A row base: m-frag i = h-row (wave_m*2 + i), w position = l32.
    int r0[2];
#pragma unroll
    for (int i = 0; i < 2; ++i)
        r0[i] = (wave_m * 2 + i) * 34 + l32;

    i32x16 acc[2];
#pragma unroll
    for (int i = 0; i < 2; i++)
#pragma unroll
        for (int r = 0; r < 16; r++) acc[i][r] = 0;

    LOAD_A(0, aP[0])
#pragma unroll
    for (int kt = 0; kt < 36; ++kt) {            // full unroll: offsets fold
        if (kt + 2 < 36) { LOAD_B(kt + 2, bP[(kt + 2) % 3]) }
        if (kt + 1 < 36) { LOAD_A(kt + 1, aP[(kt + 1) & 1]) }
        MFMA(aP[kt & 1], bP[kt % 3])
    }

    // ---- epilogue: C/D col = l32 (n), row (=w) = (reg&3)+8*(reg>>2)+4*lhi ----
    const int co = n0 + wave_n * 32 + l32;
    const float iv = __fdiv_rn(gamma[co], __fsqrt_rn(__fadd_rn(var[co], 1e-4f)));
    const float bias = __fsub_rn(beta[co], __fmul_rn(mean[co], iv));
#pragma unroll
    for (int i = 0; i < 2; ++i) {
        const int h = h0 + wave_m * 2 + i;
#pragma unroll
        for (int q = 0; q < 4; ++q) {
            const int w = q * 8 + lhi * 4;
            f32x4 v;
#pragma unroll
            for (int r = 0; r < 4; r++) {
                const float y = __fmul_rn((float)acc[i][q * 4 + r], 0.0078125f);  // exact pow2
                const float t = __fadd_rn(__fmul_rn(y, iv), bias);                // no FMA: match np
                float z2 = rintf(__fmul_rn(t, 2.f));
                z2 = fminf(fmaxf(z2, -2.f), 1.f);
                v[r] = __fmul_rn(z2, 0.5f);
            }
            *(f32x4*)(&out[(((size_t)(b * 256 + co)) * 32 + h) * 32 + w]) = v;
        }
    }
#undef LOAD_B
#undef LOAD_A
#undef MFMA
}

extern "C" void kernel_launch(void* const* d_in, const int* in_sizes, int n_in,
                              void* d_out, int out_size, void* d_ws, size_t ws_size,
                              hipStream_t stream) {
    const float* x      = (const float*)d_in[0];
    const float* weight = (const float*)d_in[1];
    const float* gamma  = (const float*)d_in[2];
    const float* beta   = (const float*)d_in[3];
    const float* rmean  = (const float*)d_in[4];
    const float* rvar   = (const float*)d_in[5];
    float* out = (float*)d_out;

    signed char* wq = (signed char*)d_ws;                   // 589,824 B (32x32 frag layout)

    wquant_kernel<<<256, 256, 0, stream>>>(weight, wq);
    conv_gemm_kernel<<<512, 512, 0, stream>>>(x, wq, gamma, beta, rmean, rvar, out);
}

// Round 10
// 120.585 us; speedup vs baseline: 1.0640x; 1.0640x over previous
//
#include <hip/hip_runtime.h>
#include <hip/hip_bf16.h>
#include <stdint.h>

// B=32, C=256, H=W=32, 3x3 conv pad 1 -> implicit GEMM in INT8.
// M = 32768 (b,h,w), N = 256 (co), K = 2304; k = (kh*3+kw)*256 + ci.
//
// Locked structure (R1/R2/R4/R8 regressed): 128x128 block, 8 waves 2m x 4n,
// 4 waves/SIMD, 16x16x64 i8 fragments; GEMM is memory/latency-bound
// (floor ~= 50MB read + 33.5MB write ~= 13.3us > 9.8us MFMA floor).
// R5 (win): B distance-2 prefetch + XCD-chunked block swizzle.
// R7 (kept): x-quant fused into GEMM staging; xpad + x-quant dispatch deleted.
// R8 (loss, reverted): 32x32x32 frags -- half-line epilogue writes broke L2
// write-combining (WRITE_SIZE 98MB vs 33.5MB out).
// R9 (crash): split-barrier staging had an OOB guard (h0+4<=32 admits h=32).
// R10 = R9 with the guard fixed (h0+4<=31): issue hh4..5 global loads FIRST,
// quant+write hh0..3 -> barrier -> write hh4..5 from regs + kt 0..11 ->
// barrier -> kt 12..35. K-loop starts after ~2/3 of staging.

typedef int i32x4 __attribute__((ext_vector_type(4)));
typedef float f32x4 __attribute__((ext_vector_type(4)));

// Weight quant: block co = 0..255 -> ternary int8, MFMA-fragment order
// B'[(co>>4)][kt][kq][co&15][j], elem = Wq[co][k=kt*64+kq*16+j].
__global__ __launch_bounds__(256) void wquant_kernel(
    const float* __restrict__ w, signed char* __restrict__ wq)
{
    __shared__ signed char wt[9 * 256];       // [khkw*256 + ci]
    const int t = threadIdx.x;
    const int co = blockIdx.x;
#pragma unroll
    for (int p = 0; p < 9; ++p) {
        const int idx = p * 256 + t;          // = ci*9 + khkw
        const float v = w[co * 2304 + idx];
        const int ci = idx / 9;
        const int khkw = idx - 9 * ci;
        const float q = fminf(fmaxf(rintf(v), -1.f), 1.f);
        wt[khkw * 256 + ci] = (signed char)(int)q;
    }
    __syncthreads();
    if (t < 144) {                            // t = kt*4 + kq
        const int kt = t >> 2, kq = t & 3;
        const uint4 v = *(const uint4*)(wt + t * 16);
        *(uint4*)(wq + ((size_t)((co >> 4) * 36 + kt) << 10) + kq * 256 + (co & 15) * 16) = v;
    }
}

// Fused conv: grid 512 (256 m-tiles x 2 n-tiles), 512 threads = 8 waves
// (2m x 4n). Wave = 64m x 32n: 4 m-frags x 2 n-frags of 16x16x64 i8.
// LDS: A halo only, 6 rows x 34 wp x 256 ci = 52,224 B, xor-swizzled chunks,
// built in-kernel from x (quant fused into staging, split-barrier).
__global__ __launch_bounds__(512, 4) void conv_gemm_kernel(
    const float* __restrict__ x, const signed char* __restrict__ wqm,
    const float* __restrict__ gamma, const float* __restrict__ beta,
    const float* __restrict__ mean, const float* __restrict__ var,
    float* __restrict__ out)
{
    __shared__ signed char As[6 * 34 * 256];   // [r=hh*34+wp][chunk ^ (r&15)][16]

    const int tid = threadIdx.x;
    const int wv = tid >> 6;
    const int lane = tid & 63;
    const int l16 = lane & 15;
    const int l4 = lane >> 4;

    // XCD-chunked bijective swizzle (512 = 8 x 64): XCD g gets swz 64g..64g+63.
    const int bid = (int)blockIdx.x;
    const int swz = (bid & 7) * 64 + (bid >> 3);

    const int mt = swz >> 1;
    const int n0 = (swz & 1) * 128;
    const int b = mt >> 3;
    const int h0 = (mt & 7) * 4;
    const int wave_m = wv & 1;    // 2 waves over m (64 each)
    const int wave_n = wv >> 1;   // 4 waves over n (32 each)

    // B pointers + first prefetches issued before staging (independent of LDS)
    const signed char* bp0 = wqm + (((size_t)((n0 >> 4) + wave_n * 2 + 0) * 36) << 10) + lane * 16;
    const signed char* bp1 = wqm + (((size_t)((n0 >> 4) + wave_n * 2 + 1) * 36) << 10) + lane * 16;

    i32x4 aP[2][4], bP[3][2];                    // B: distance-2 triple buffer

#define LOAD_B(kt, dst) { dst[0] = *(const i32x4*)(bp0 + (kt) * 1024); \
                          dst[1] = *(const i32x4*)(bp1 + (kt) * 1024); }
#define LOAD_A(kt, dst) { const int khkw = (kt) >> 2; \
                          const int kh = khkw / 3; \
                          const int kw = khkw - 3 * kh; \
                          const int roff = kh * 34 + kw; \
                          const int cb = ((kt) & 3) * 4 + l4; \
                          _Pragma("unroll") \
                          for (int i = 0; i < 4; ++i) { \
                              const int r = r0[i] + roff; \
                              dst[i] = *(const i32x4*)(As + r * 256 + ((cb ^ (r & 15)) << 4)); \
                          } }
#define MFMA(af, bf) { _Pragma("unroll") \
                       for (int i = 0; i < 4; ++i) \
                           _Pragma("unroll") \
                           for (int j = 0; j < 2; ++j) \
                               acc[i][j] = __builtin_amdgcn_mfma_i32_16x16x64_i8(af[i], bf[j], acc[i][j], 0, 0, 0); }
// quantize a 4ci x 4w f32 block and transpose to 4 packed words
#define QUANT_TR(vsrc, col) { unsigned row[4]; \
        _Pragma("unroll") \
        for (int j = 0; j < 4; ++j) { \
            unsigned p = 0; \
            _Pragma("unroll") \
            for (int k = 0; k < 4; ++k) { \
                const float q = fminf(fmaxf(rintf(__fmul_rn(vsrc[j][k], 128.f)), -128.f), 127.f); \
                p |= ((unsigned)(unsigned char)(signed char)(int)q) << (8 * k); \
            } \
            row[j] = p; \
        } \
        const unsigned ab_lo = __builtin_amdgcn_perm(row[1], row[0], 0x05010400u); \
        const unsigned ab_hi = __builtin_amdgcn_perm(row[1], row[0], 0x07030602u); \
        const unsigned cd_lo = __builtin_amdgcn_perm(row[3], row[2], 0x05010400u); \
        const unsigned cd_hi = __builtin_amdgcn_perm(row[3], row[2], 0x07030602u); \
        col[0] = __builtin_amdgcn_perm(cd_lo, ab_lo, 0x05040100u); \
        col[1] = __builtin_amdgcn_perm(cd_lo, ab_lo, 0x07060302u); \
        col[2] = __builtin_amdgcn_perm(cd_hi, ab_hi, 0x05040100u); \
        col[3] = __builtin_amdgcn_perm(cd_hi, ab_hi, 0x07060302u); }

    LOAD_B(0, bP[0])
    LOAD_B(1, bP[1])

    const int cib = tid >> 3;                  // 0..63 (ci0 = 4*cib)
    const int w4 = tid & 7;                    // 0..7  (w = w4*4 .. +3)

    // ---- phase-2 global loads FIRST (hh 4..5): latency hides under phase-1 ----
    f32x4 ph2[2][4];
    const bool p2v1 = (h0 + 4 <= 31);          // hh=5 -> h = h0+4; h0=28 is border
#pragma unroll
    for (int u = 0; u < 2; ++u) {
        const int h = h0 + 3 + u;              // hh = 4+u
        if (u == 1 && !p2v1) continue;         // block-uniform
        const float* xb = x + ((size_t)(b * 256) * 32 + h) * 32;
#pragma unroll
        for (int j = 0; j < 4; ++j)
            ph2[u][j] = *(const f32x4*)(xb + (size_t)(cib * 4 + j) * 1024 + w4 * 4);
    }

    // ---- staging: zero borders ----
    const uint4 z = {0u, 0u, 0u, 0u};
    if (tid < 192) {                           // wp=0,33 cols of the 6 rows
        const int pair = tid >> 4;             // (hh 0..5) x (wp 0|33)
        const int hh = pair >> 1;
        const int wp = (pair & 1) * 33;
        const bool covered = (h0 == 0 && hh == 0) || (h0 == 28 && hh == 5);
        if (!covered) {
            const int r = hh * 34 + wp;
            const int ch = tid & 15;
            *(uint4*)(As + r * 256 + ((ch ^ (r & 15)) << 4)) = z;
        }
    }
    if (h0 == 0) {                             // halo row above image: all zero
        for (int i = tid; i < 544; i += 512) {
            const int r = i >> 4;
            const int ch = i & 15;
            *(uint4*)(As + r * 256 + ((ch ^ (r & 15)) << 4)) = z;
        }
    }
    if (h0 == 28) {                            // halo row below image: all zero
        for (int i = tid; i < 544; i += 512) {
            const int r = 5 * 34 + (i >> 4);
            const int ch = i & 15;
            *(uint4*)(As + r * 256 + ((ch ^ (r & 15)) << 4)) = z;
        }
    }

    // ---- phase-1: fused x-quant rows hh 0..3 (all kh=0 needs) ----
#pragma unroll
    for (int hh = 0; hh < 4; ++hh) {
        const int h = h0 + hh - 1;
        if (h < 0) continue;                   // block-uniform (h0==0, hh==0)
        const float* xb = x + ((size_t)(b * 256) * 32 + h) * 32;
        f32x4 vsrc[4];
#pragma unroll
        for (int j = 0; j < 4; ++j)
            vsrc[j] = *(const f32x4*)(xb + (size_t)(cib * 4 + j) * 1024 + w4 * 4);
        unsigned col[4];
        QUANT_TR(vsrc, col)
#pragma unroll
        for (int r = 0; r < 4; ++r) {
            const int rr = hh * 34 + w4 * 4 + r + 1;   // wp = w+1 in 1..32
            *(unsigned*)(As + rr * 256 + (((cib >> 2) ^ (rr & 15)) << 4) + (cib & 3) * 4) = col[r];
        }
    }
    __syncthreads();   // barrier 1: rows 0..3 (+ all borders) resident

    int r0[4];
#pragma unroll
    for (int i = 0; i < 4; ++i)
        r0[i] = (wave_m * 2 + (i >> 1)) * 34 + (i & 1) * 16 + l16;

    i32x4 acc[4][2];
#pragma unroll
    for (int i = 0; i < 4; i++)
#pragma unroll
        for (int j = 0; j < 2; j++) acc[i][j] = (i32x4){0, 0, 0, 0};

    LOAD_A(0, aP[0])

    // ---- phase-2 writes (rows hh 4..5, data already in regs) ----
#pragma unroll
    for (int u = 0; u < 2; ++u) {
        if (u == 1 && !p2v1) continue;
        const int hh = 4 + u;
        unsigned col[4];
        QUANT_TR(ph2[u], col)
#pragma unroll
        for (int r = 0; r < 4; ++r) {
            const int rr = hh * 34 + w4 * 4 + r + 1;
            *(unsigned*)(As + rr * 256 + (((cib >> 2) ^ (rr & 15)) << 4) + (cib & 3) * 4) = col[r];
        }
    }

    // ---- K-loop part 1: kt 0..11 (kh=0, reads rows hh 0..3 only) ----
#pragma unroll
    for (int kt = 0; kt < 11; ++kt) {
        LOAD_B(kt + 2, bP[(kt + 2) % 3])
        LOAD_A(kt + 1, aP[(kt + 1) & 1])
        MFMA(aP[kt & 1], bP[kt % 3])
    }
    LOAD_B(13, bP[1])                           // 13 % 3 == 1
    MFMA(aP[1], bP[2])                          // kt=11: aP[11&1], bP[11%3]
    __syncthreads();   // barrier 2: rows hh 4..5 resident

    // ---- K-loop part 2: kt 12..35 ----
    LOAD_A(12, aP[0])
#pragma unroll
    for (int kt = 12; kt < 36; ++kt) {
        if (kt + 2 < 36) { LOAD_B(kt + 2, bP[(kt + 2) % 3]) }
        if (kt + 1 < 36) { LOAD_A(kt + 1, aP[(kt + 1) & 1]) }
        MFMA(aP[kt & 1], bP[kt % 3])
    }

    // ---- epilogue: C/D col = l16 (n), row = l4*4 + r (m within frag) ----
#pragma unroll
    for (int j = 0; j < 2; ++j) {
        const int co = n0 + wave_n * 32 + j * 16 + l16;
        const float iv = __fdiv_rn(gamma[co], __fsqrt_rn(__fadd_rn(var[co], 1e-4f)));
        const float bias = __fsub_rn(beta[co], __fmul_rn(mean[co], iv));
#pragma unroll
        for (int i = 0; i < 4; ++i) {
            const int h = h0 + wave_m * 2 + (i >> 1);
            const int w = (i & 1) * 16 + l4 * 4;
            f32x4 v;
#pragma unroll
            for (int r = 0; r < 4; r++) {
                const float y = __fmul_rn((float)acc[i][j][r], 0.0078125f);  // exact pow2
                const float t = __fadd_rn(__fmul_rn(y, iv), bias);           // no FMA: match np
                float z2 = rintf(__fmul_rn(t, 2.f));
                z2 = fminf(fmaxf(z2, -2.f), 1.f);
                v[r] = __fmul_rn(z2, 0.5f);
            }
            *(f32x4*)(&out[(((size_t)(b * 256 + co)) * 32 + h) * 32 + w]) = v;
        }
    }
#undef LOAD_B
#undef LOAD_A
#undef MFMA
#undef QUANT_TR
}

extern "C" void kernel_launch(void* const* d_in, const int* in_sizes, int n_in,
                              void* d_out, int out_size, void* d_ws, size_t ws_size,
                              hipStream_t stream) {
    const float* x      = (const float*)d_in[0];
    const float* weight = (const float*)d_in[1];
    const float* gamma  = (const float*)d_in[2];
    const float* beta   = (const float*)d_in[3];
    const float* rmean  = (const float*)d_in[4];
    const float* rvar   = (const float*)d_in[5];
    float* out = (float*)d_out;

    signed char* wq = (signed char*)d_ws;                   // 589,824 B (MFMA layout)

    wquant_kernel<<<256, 256, 0, stream>>>(weight, wq);
    conv_gemm_kernel<<<512, 512, 0, stream>>>(x, wq, gamma, beta, rmean, rvar, out);
}

// Round 11
// 109.590 us; speedup vs baseline: 1.1708x; 1.1003x over previous
//
#include <hip/hip_runtime.h>
#include <hip/hip_bf16.h>
#include <stdint.h>

// B=32, C=256, H=W=32, 3x3 conv pad 1 -> implicit GEMM in INT8.
// M = 32768 (b,h,w), N = 256 (co), K = 2304; k = (kh*3+kw)*256 + ci.
//
// Locked per-wave structure (R1/R2/R4/R8/R10 regressed): wave = 64m x 32n,
// 4 m-frags x 2 n-frags 16x16x64 i8, 4 waves/SIMD, single post-staging
// barrier, B distance-2 prefetch, XCD-chunked swizzle (R5 win).
// R7 (kept): x-quant fused into GEMM staging; xpad deleted.
// R11: deduplicate staging. One 1024-thread block (16 waves, 2m x 8n) per
// m-tile covers the FULL N=256, so each A-halo is quantized ONCE (R7: twice,
// once per n0-pair block). Per-wave inner loop byte-identical to R7; TLP
// unchanged (16 waves/CU); staging per thread halves (3 rows not 6);
// machine-wide x fetch + quant VALU + ds_writes halve.

typedef int i32x4 __attribute__((ext_vector_type(4)));
typedef float f32x4 __attribute__((ext_vector_type(4)));

// Weight quant: block co = 0..255 -> ternary int8, MFMA-fragment order
// B'[(co>>4)][kt][kq][co&15][j], elem = Wq[co][k=kt*64+kq*16+j].
__global__ __launch_bounds__(256) void wquant_kernel(
    const float* __restrict__ w, signed char* __restrict__ wq)
{
    __shared__ signed char wt[9 * 256];       // [khkw*256 + ci]
    const int t = threadIdx.x;
    const int co = blockIdx.x;
#pragma unroll
    for (int p = 0; p < 9; ++p) {
        const int idx = p * 256 + t;          // = ci*9 + khkw
        const float v = w[co * 2304 + idx];
        const int ci = idx / 9;
        const int khkw = idx - 9 * ci;
        const float q = fminf(fmaxf(rintf(v), -1.f), 1.f);
        wt[khkw * 256 + ci] = (signed char)(int)q;
    }
    __syncthreads();
    if (t < 144) {                            // t = kt*4 + kq
        const int kt = t >> 2, kq = t & 3;
        const uint4 v = *(const uint4*)(wt + t * 16);
        *(uint4*)(wq + ((size_t)((co >> 4) * 36 + kt) << 10) + kq * 256 + (co & 15) * 16) = v;
    }
}

// Fused conv: grid 256 (one per m-tile), 1024 threads = 16 waves (2m x 8n).
// Block = 128m x 256n. Wave = 64m x 32n: 4 m-frags x 2 n-frags of 16x16x64.
// LDS: A halo only, 6 rows x 34 wp x 256 ci = 52,224 B, xor-swizzled chunks,
// built in-kernel from x (quant fused into staging, staged ONCE per halo).
__global__ __launch_bounds__(1024, 4) void conv_gemm_kernel(
    const float* __restrict__ x, const signed char* __restrict__ wqm,
    const float* __restrict__ gamma, const float* __restrict__ beta,
    const float* __restrict__ mean, const float* __restrict__ var,
    float* __restrict__ out)
{
    __shared__ signed char As[6 * 34 * 256];   // [r=hh*34+wp][chunk ^ (r&15)][16]

    const int tid = threadIdx.x;
    const int wv = tid >> 6;                   // 0..15
    const int lane = tid & 63;
    const int l16 = lane & 15;
    const int l4 = lane >> 4;

    // XCD-chunked bijective swizzle (256 = 8 x 32): XCD g gets mt 32g..32g+31.
    const int bid = (int)blockIdx.x;
    const int mt = (bid & 7) * 32 + (bid >> 3);

    const int b = mt >> 3;
    const int h0 = (mt & 7) * 4;
    const int wave_m = wv & 1;    // 2 waves over m (64 each)
    const int wave_n = wv >> 1;   // 8 waves over n (32 each)

    // B pointers + first prefetches issued before staging (independent of LDS)
    const signed char* bp0 = wqm + (((size_t)(wave_n * 2 + 0) * 36) << 10) + lane * 16;
    const signed char* bp1 = wqm + (((size_t)(wave_n * 2 + 1) * 36) << 10) + lane * 16;

    i32x4 aP[2][4], bP[3][2];                    // B: distance-2 triple buffer

#define LOAD_B(kt, dst) { dst[0] = *(const i32x4*)(bp0 + (kt) * 1024); \
                          dst[1] = *(const i32x4*)(bp1 + (kt) * 1024); }
#define LOAD_A(kt, dst) { const int khkw = (kt) >> 2; \
                          const int kh = khkw / 3; \
                          const int kw = khkw - 3 * kh; \
                          const int roff = kh * 34 + kw; \
                          const int cb = ((kt) & 3) * 4 + l4; \
                          _Pragma("unroll") \
                          for (int i = 0; i < 4; ++i) { \
                              const int r = r0[i] + roff; \
                              dst[i] = *(const i32x4*)(As + r * 256 + ((cb ^ (r & 15)) << 4)); \
                          } }
#define MFMA(af, bf) { _Pragma("unroll") \
                       for (int i = 0; i < 4; ++i) \
                           _Pragma("unroll") \
                           for (int j = 0; j < 2; ++j) \
                               acc[i][j] = __builtin_amdgcn_mfma_i32_16x16x64_i8(af[i], bf[j], acc[i][j], 0, 0, 0); }

    LOAD_B(0, bP[0])
    LOAD_B(1, bP[1])

    // ---- staging: zero borders ----
    const uint4 z = {0u, 0u, 0u, 0u};
    if (tid < 192) {                           // wp=0,33 cols of the 6 rows
        const int pair = tid >> 4;             // (hh 0..5) x (wp 0|33)
        const int hh = pair >> 1;
        const int wp = (pair & 1) * 33;
        const bool covered = (h0 == 0 && hh == 0) || (h0 == 28 && hh == 5);
        if (!covered) {
            const int r = hh * 34 + wp;
            const int ch = tid & 15;
            *(uint4*)(As + r * 256 + ((ch ^ (r & 15)) << 4)) = z;
        }
    }
    if (h0 == 0) {                             // halo row above image: all zero
        for (int i = tid; i < 544; i += 1024) {
            const int r = i >> 4;
            const int ch = i & 15;
            *(uint4*)(As + r * 256 + ((ch ^ (r & 15)) << 4)) = z;
        }
    }
    if (h0 == 28) {                            // halo row below image: all zero
        for (int i = tid; i < 544; i += 1024) {
            const int r = 5 * 34 + (i >> 4);
            const int ch = i & 15;
            *(uint4*)(As + r * 256 + ((ch ^ (r & 15)) << 4)) = z;
        }
    }

    // ---- staging: fused x-quant; each half of the block does 3 rows ----
    const int half = tid >> 9;                 // 0: hh 0..2, 1: hh 3..5
    const int st = tid & 511;
    const int cib = st >> 3;                   // 0..63 (ci0 = 4*cib)
    const int w4 = st & 7;                     // 0..7  (w = w4*4 .. +3)
#pragma unroll
    for (int hq = 0; hq < 3; ++hq) {
        const int hh = half * 3 + hq;
        const int h = h0 + hh - 1;
        if (h < 0 || h > 31) continue;         // half-uniform branch
        const float* xb = x + ((size_t)(b * 256) * 32 + h) * 32;
        unsigned row[4];                       // row[j] byte k = Q[ci0+j][w4*4+k]
#pragma unroll
        for (int j = 0; j < 4; ++j) {
            const f32x4 v = *(const f32x4*)(xb + (size_t)(cib * 4 + j) * 1024 + w4 * 4);
            unsigned p = 0;
#pragma unroll
            for (int k = 0; k < 4; ++k) {
                const float q = fminf(fmaxf(rintf(__fmul_rn(v[k], 128.f)), -128.f), 127.f);
                p |= ((unsigned)(unsigned char)(signed char)(int)q) << (8 * k);
            }
            row[j] = p;
        }
        // 4x4 byte transpose: col[r] = [Q[ci0][w], Q[ci0+1][w], ..] for w=w4*4+r
        const unsigned ab_lo = __builtin_amdgcn_perm(row[1], row[0], 0x05010400u);
        const unsigned ab_hi = __builtin_amdgcn_perm(row[1], row[0], 0x07030602u);
        const unsigned cd_lo = __builtin_amdgcn_perm(row[3], row[2], 0x05010400u);
        const unsigned cd_hi = __builtin_amdgcn_perm(row[3], row[2], 0x07030602u);
        unsigned col[4];
        col[0] = __builtin_amdgcn_perm(cd_lo, ab_lo, 0x05040100u);
        col[1] = __builtin_amdgcn_perm(cd_lo, ab_lo, 0x07060302u);
        col[2] = __builtin_amdgcn_perm(cd_hi, ab_hi, 0x05040100u);
        col[3] = __builtin_amdgcn_perm(cd_hi, ab_hi, 0x07060302u);
#pragma unroll
        for (int r = 0; r < 4; ++r) {
            const int rr = hh * 34 + w4 * 4 + r + 1;   // wp = w+1 in 1..32
            *(unsigned*)(As + rr * 256 + (((cib >> 2) ^ (rr & 15)) << 4) + (cib & 3) * 4) = col[r];
        }
    }
    __syncthreads();   // the ONLY barrier

    int r0[4];
#pragma unroll
    for (int i = 0; i < 4; ++i)
        r0[i] = (wave_m * 2 + (i >> 1)) * 34 + (i & 1) * 16 + l16;

    i32x4 acc[4][2];
#pragma unroll
    for (int i = 0; i < 4; i++)
#pragma unroll
        for (int j = 0; j < 2; j++) acc[i][j] = (i32x4){0, 0, 0, 0};

    LOAD_A(0, aP[0])
#pragma unroll
    for (int kt = 0; kt < 36; ++kt) {            // full unroll: offsets fold
        if (kt + 2 < 36) { LOAD_B(kt + 2, bP[(kt + 2) % 3]) }
        if (kt + 1 < 36) { LOAD_A(kt + 1, aP[(kt + 1) & 1]) }
        MFMA(aP[kt & 1], bP[kt % 3])
    }

    // ---- epilogue: C/D col = l16 (n), row = l4*4 + r (m within frag) ----
#pragma unroll
    for (int j = 0; j < 2; ++j) {
        const int co = wave_n * 32 + j * 16 + l16;
        const float iv = __fdiv_rn(gamma[co], __fsqrt_rn(__fadd_rn(var[co], 1e-4f)));
        const float bias = __fsub_rn(beta[co], __fmul_rn(mean[co], iv));
#pragma unroll
        for (int i = 0; i < 4; ++i) {
            const int h = h0 + wave_m * 2 + (i >> 1);
            const int w = (i & 1) * 16 + l4 * 4;
            f32x4 v;
#pragma unroll
            for (int r = 0; r < 4; r++) {
                const float y = __fmul_rn((float)acc[i][j][r], 0.0078125f);  // exact pow2
                const float t = __fadd_rn(__fmul_rn(y, iv), bias);           // no FMA: match np
                float z2 = rintf(__fmul_rn(t, 2.f));
                z2 = fminf(fmaxf(z2, -2.f), 1.f);
                v[r] = __fmul_rn(z2, 0.5f);
            }
            *(f32x4*)(&out[(((size_t)(b * 256 + co)) * 32 + h) * 32 + w]) = v;
        }
    }
#undef LOAD_B
#undef LOAD_A
#undef MFMA
}

extern "C" void kernel_launch(void* const* d_in, const int* in_sizes, int n_in,
                              void* d_out, int out_size, void* d_ws, size_t ws_size,
                              hipStream_t stream) {
    const float* x      = (const float*)d_in[0];
    const float* weight = (const float*)d_in[1];
    const float* gamma  = (const float*)d_in[2];
    const float* beta   = (const float*)d_in[3];
    const float* rmean  = (const float*)d_in[4];
    const float* rvar   = (const float*)d_in[5];
    float* out = (float*)d_out;

    signed char* wq = (signed char*)d_ws;                   // 589,824 B (MFMA layout)

    wquant_kernel<<<256, 256, 0, stream>>>(weight, wq);
    conv_gemm_kernel<<<256, 1024, 0, stream>>>(x, wq, gamma, beta, rmean, rvar, out);
}